// Round 10
// baseline (896.905 us; speedup 1.0000x reference)
//
#include <hip/hip_runtime.h>

#define IN_DIM   128
#define OUT_DIM  128
#define ATTN_DIM 64
#define N_RELV   401
#define N_NODE   50000
#define N_EDGE   500000
#define N_QUERY  64
#define N_DT     731
#define NCH      196      // ceil(50000/256) scan chunks
#define MEGA_NB  768      // co-resident guaranteed: launch_bounds(256,4) -> 4 blk/CU * 256 CU = 1024 >= 768

typedef unsigned short ushort_t;
typedef unsigned int   uint_t;
typedef __attribute__((ext_vector_type(8))) short v8s;   // 8 bf16 (4 VGPRs)
typedef __attribute__((ext_vector_type(4))) float v4f;

__device__ __forceinline__ int clampi(int v, int lo, int hi) {
    return v < lo ? lo : (v > hi ? hi : v);
}
__device__ __forceinline__ float bu2f(ushort_t u) {
    union { uint_t i; float f; } v; v.i = ((uint_t)u) << 16; return v.f;
}
__device__ __forceinline__ float blo(uint_t u) { return bu2f((ushort_t)(u & 0xffff)); }
__device__ __forceinline__ float bhi(uint_t u) { return bu2f((ushort_t)(u >> 16)); }
__device__ __forceinline__ ushort_t f2bu(float f) {   // RNE, finite inputs
    union { float f; uint_t i; } v; v.f = f;
    const uint_t x = v.i;
    return (ushort_t)((x + 0x7fffu + ((x >> 16) & 1u)) >> 16);
}

__device__ __forceinline__ void parse_edge(const int* __restrict__ edges, int e,
                                           int i64, int& r, int& rel, int& tau,
                                           int& sub, int& obj) {
    if (i64) {
        const int* E = edges + (size_t)e * 14;
        r = E[0]; rel = E[4]; tau = E[8]; sub = E[10]; obj = E[12];
    } else {
        const int* E = edges + (size_t)e * 7;
        r = E[0]; rel = E[2]; tau = E[4]; sub = E[5]; obj = E[6];
    }
    r   = clampi(r,   0, N_QUERY - 1);
    rel = clampi(rel, 0, N_RELV - 1);
    sub = clampi(sub, 0, N_NODE - 1);
    obj = clampi(obj, 0, N_NODE - 1);
}

// Manual grid barrier. Safe ONLY because MEGA_NB blocks are guaranteed
// co-resident (launch_bounds(256,4) => >=1024 blocks resident).
// Classic syncthreads + agent fence + device-scope counter pattern
// (same structure ROCm's own grid sync uses).
__device__ __forceinline__ void grid_barrier(int* bar, int slot, int nblk)
{
    __syncthreads();
    if (threadIdx.x == 0) {
        __threadfence();                         // agent-scope release (wb L2)
        atomicAdd(&bar[slot], 1);                // device-scope
        while (__hip_atomic_load(&bar[slot], __ATOMIC_ACQUIRE,
                                 __HIP_MEMORY_SCOPE_AGENT) < nblk) {
            __builtin_amdgcn_s_sleep(2);
        }
        __threadfence();                         // acquire side (inv caches)
    }
    __syncthreads();
}

// ---------------------------------------------------------------------------
// K0: one-block init — detect int width, build WTb, zero deg + barrier slots.
// ---------------------------------------------------------------------------
__global__ __launch_bounds__(256) void init_kernel(
    const int* __restrict__ edges, const float* __restrict__ Ws,
    const float* __restrict__ Wh,
    int* __restrict__ flag, int* __restrict__ bar,
    ushort_t* __restrict__ WTb, int* __restrict__ deg)
{
    const int tid = threadIdx.x;
    __shared__ int bad;
    if (tid == 0) bad = 0;
    if (tid < 16) bar[tid] = 0;
    __syncthreads();
    for (int i = tid; i < 1000; i += 256) {
        const int w = edges[2 * i + 1];
        if (w != 0 && w != -1) bad = 1;
    }
    __syncthreads();
    if (tid == 0) flag[0] = (bad == 0) ? 1 : 0;

    for (int i = tid; i < 192 * 128; i += 256) {
        const int n = i >> 7, k = i & 127;
        const float w = (n < 64) ? Ws[k * 64 + n] : Wh[k * 128 + (n - 64)];
        WTb[i] = f2bu(w);
    }
    for (int i = tid; i < N_NODE; i += 256) deg[i] = 0;
}

// ---------------------------------------------------------------------------
// K1: mega front — phases with manual grid barriers:
//   P1: node MFMA tabs + rel/dt/qr tabs + degree histogram
//   P2: per-chunk exclusive scan   P3: chunk-sum scan (block 0)
//   P4: add base -> offs, cursor
// ---------------------------------------------------------------------------
struct MegaArgs {
    const int*   edges; const int* q_rel; const int* q_tau;
    const float* hidden; const float* rela;
    const float* Wr; const float* WqrW; const float* Wqrb;
    const float* Wtau; const float* Wh;
    const float* wt1; const float* bt1; const float* wt2; const float* bt2;
    int* flag; int* bar;
    ushort_t* WTb; ushort_t* XqrB;
    ushort_t* rel_attn; ushort_t* rel_msg;
    ushort_t* dt_attn;  ushort_t* dt_msg;
    ushort_t* node_attn; ushort_t* node_msg;
    int* deg; int* offs; int* cursor; int* chunksum; int* chunkbase;
};

__global__ __launch_bounds__(256, 4) void mega_front(MegaArgs a)
{
    const int nb  = MEGA_NB;
    const int bid = blockIdx.x;
    const int tid = threadIdx.x;
    const int gsz = nb * 256;
    const int gix = bid * 256 + tid;

    __shared__ float hbuf[4][IN_DIM];
    __shared__ int   s[256];

    // ---------------- P1: tabs + hist ----------------
    {   // node MFMA projection (LDS-free), 782 units of 64 rows
        const int wid  = tid >> 6;
        const int lane = tid & 63;
        const int m16  = lane & 15;
        const int q    = lane >> 4;
        for (int u = bid; u < (N_NODE + 63) / 64; u += nb) {
            const int nbase = u * 64;
            const int row   = nbase + wid * 16 + m16;
            const int rowc  = row < N_NODE ? row : N_NODE - 1;
            v8s afr[4];
            #pragma unroll
            for (int c = 0; c < 4; ++c) {
                const float4 f0 = *(const float4*)(a.hidden + (size_t)rowc * 128 + 32 * c + 8 * q);
                const float4 f1 = *(const float4*)(a.hidden + (size_t)rowc * 128 + 32 * c + 8 * q + 4);
                v8s v;
                v[0] = (short)f2bu(f0.x); v[1] = (short)f2bu(f0.y);
                v[2] = (short)f2bu(f0.z); v[3] = (short)f2bu(f0.w);
                v[4] = (short)f2bu(f1.x); v[5] = (short)f2bu(f1.y);
                v[6] = (short)f2bu(f1.z); v[7] = (short)f2bu(f1.w);
                afr[c] = v;
            }
            #pragma unroll
            for (int t = 0; t < 12; ++t) {
                v4f acc = {0.f, 0.f, 0.f, 0.f};
                #pragma unroll
                for (int c = 0; c < 4; ++c) {
                    const v8s bfr = *(const v8s*)(a.WTb + (size_t)(16 * t + m16) * 128 + 32 * c + 8 * q);
                    acc = __builtin_amdgcn_mfma_f32_16x16x32_bf16(afr[c], bfr, acc, 0, 0, 0);
                }
                #pragma unroll
                for (int r = 0; r < 4; ++r) {
                    const int node = nbase + wid * 16 + 4 * q + r;
                    if (node < N_NODE) {
                        const int col = 16 * t + m16;
                        if (col < 64) a.node_attn[(size_t)node * 64  + col]        = f2bu(acc[r]);
                        else          a.node_msg [(size_t)node * 128 + (col - 64)] = f2bu(acc[r]);
                    }
                }
            }
        }
    }
    {   // rel tabs, 2 per block
        const int half = tid >> 7, t = tid & 127;
        for (int u = bid; u < (N_RELV + 1) / 2; u += nb) {
            const int r = 2 * u + half;
            if (r < N_RELV) hbuf[half][t] = a.rela[(size_t)r * IN_DIM + t];
            __syncthreads();
            if (r < N_RELV) {
                if (t < ATTN_DIM) {
                    float x = 0.f;
                    #pragma unroll 8
                    for (int d = 0; d < IN_DIM; ++d) x += hbuf[half][d] * a.Wr[d * ATTN_DIM + t];
                    a.rel_attn[(size_t)r * ATTN_DIM + t] = f2bu(x);
                }
                float m = 0.f;
                #pragma unroll 8
                for (int d = 0; d < IN_DIM; ++d) m += hbuf[half][d] * a.Wh[d * OUT_DIM + t];
                a.rel_msg[(size_t)r * OUT_DIM + t] = f2bu(m);
            }
            __syncthreads();
        }
    }
    {   // dt tabs, 2 per block
        const int half = tid >> 7, t = tid & 127;
        for (int u = bid; u < (N_DT + 1) / 2; u += nb) {
            const int i = 2 * u + half;
            if (i < N_DT) {
                const float dt = (float)(i - 365);
                hbuf[half][t] = a.wt1[t] * dt + a.bt1[t] + sinf(a.wt2[t] * dt + a.bt2[t]);
            }
            __syncthreads();
            if (i < N_DT) {
                if (t < ATTN_DIM) {
                    float x = 0.f;
                    #pragma unroll 8
                    for (int d = 0; d < IN_DIM; ++d) x += hbuf[half][d] * a.Wtau[d * ATTN_DIM + t];
                    a.dt_attn[(size_t)i * ATTN_DIM + t] = f2bu(x);
                }
                float m = 0.f;
                #pragma unroll 8
                for (int d = 0; d < IN_DIM; ++d) m += hbuf[half][d] * a.Wh[d * OUT_DIM + t];
                a.dt_msg[(size_t)i * OUT_DIM + t] = f2bu(m);
            }
            __syncthreads();
        }
    }
    {   // qr tab, 4 per block (16 units)
        const int sq = tid >> 6, lane = tid & 63;
        const int i64 = a.flag[0];
        for (int u = bid; u < N_QUERY / 4; u += nb) {
            const int qq  = 4 * u + sq;
            const int rel = clampi(a.q_rel[i64 ? 2 * qq : qq], 0, N_RELV - 1);
            const float2 v = ((const float2*)(a.rela + (size_t)rel * IN_DIM))[lane];
            hbuf[sq][2 * lane] = v.x; hbuf[sq][2 * lane + 1] = v.y;
            __syncthreads();
            float acc = a.Wqrb[lane];
            #pragma unroll 8
            for (int d = 0; d < IN_DIM; ++d) acc += hbuf[sq][d] * a.WqrW[d * ATTN_DIM + lane];
            a.XqrB[(size_t)qq * ATTN_DIM + lane] = f2bu(acc);
            __syncthreads();
        }
    }
    {   // degree histogram
        const int i64 = a.flag[0];
        for (int e = gix; e < N_EDGE; e += gsz) {
            int obj = i64 ? a.edges[(size_t)e * 14 + 12] : a.edges[(size_t)e * 7 + 6];
            obj = clampi(obj, 0, N_NODE - 1);
            atomicAdd(&a.deg[obj], 1);
        }
    }
    grid_barrier(a.bar, 0, nb);

    // ---------------- P2: per-chunk scan ----------------
    for (int u = bid; u < NCH; u += nb) {
        const int i = u * 256 + tid;
        const int v = (i < N_NODE) ? a.deg[i] : 0;
        int acc = v;
        s[tid] = acc; __syncthreads();
        #pragma unroll
        for (int o = 1; o < 256; o <<= 1) {
            const int t = (tid >= o) ? s[tid - o] : 0;
            __syncthreads();
            acc += t; s[tid] = acc;
            __syncthreads();
        }
        if (i < N_NODE) a.offs[i] = acc - v;
        if (tid == 255) a.chunksum[u] = acc;
        __syncthreads();
    }
    grid_barrier(a.bar, 1, nb);

    // ---------------- P3: chunk-sum scan (block 0) ----------------
    if (bid == 0) {
        const int v = (tid < NCH) ? a.chunksum[tid] : 0;
        int acc = v;
        s[tid] = acc; __syncthreads();
        #pragma unroll
        for (int o = 1; o < 256; o <<= 1) {
            const int t = (tid >= o) ? s[tid - o] : 0;
            __syncthreads();
            acc += t; s[tid] = acc;
            __syncthreads();
        }
        if (tid < NCH) a.chunkbase[tid] = acc - v;
        if (tid == 0)  a.offs[N_NODE] = N_EDGE;
    }
    grid_barrier(a.bar, 2, nb);

    // ---------------- P4: add base ----------------
    for (int u = bid; u < NCH; u += nb) {
        const int i = u * 256 + tid;
        if (i < N_NODE) {
            const int o = a.offs[i] + a.chunkbase[u];
            a.offs[i]   = o;
            a.cursor[i] = o;
        }
    }
}

// ---------------------------------------------------------------------------
// K2: per-edge alpha. 16 lanes per edge (4 edges/wave).
// meta.x = sub | (di<<17), meta.y = rel, metaW = alpha.
// ---------------------------------------------------------------------------
__global__ __launch_bounds__(256) void alpha_kernel(
    const int* __restrict__ edges, const int* __restrict__ q_tau,
    const ushort_t* __restrict__ node_attn, const ushort_t* __restrict__ rel_attn,
    const ushort_t* __restrict__ dt_attn,  const ushort_t* __restrict__ Xqr,
    const float* __restrict__ w_alpha_W, const float* __restrict__ w_alpha_b,
    const int* __restrict__ flag, int* __restrict__ cursor,
    int2* __restrict__ metaA, float* __restrict__ metaW)
{
    const int g   = threadIdx.x & 15;
    const int e   = blockIdx.x * 16 + (threadIdx.x >> 4);
    const int i64 = flag[0];

    int r, rel, tau, sub, obj;
    parse_edge(edges, e, i64, r, rel, tau, sub, obj);
    const int tq = q_tau[i64 ? 2 * r : r];
    if (tau < 0) tau = tq;
    const int di = clampi(tau - tq + 365, 0, N_DT - 1);

    const uint2 xs = *(const uint2*)(node_attn + (size_t)sub * ATTN_DIM + 4 * g);
    const uint2 xr = *(const uint2*)(rel_attn + (size_t)rel * ATTN_DIM + 4 * g);
    const uint2 xt = *(const uint2*)(dt_attn  + (size_t)di  * ATTN_DIM + 4 * g);
    const uint2 xq = *(const uint2*)(Xqr      + (size_t)r   * ATTN_DIM + 4 * g);
    const float4 w = *(const float4*)(w_alpha_W + 4 * g);

    const float s0 = blo(xs.x) + blo(xr.x) + blo(xt.x) + blo(xq.x);
    const float s1 = bhi(xs.x) + bhi(xr.x) + bhi(xt.x) + bhi(xq.x);
    const float s2 = blo(xs.y) + blo(xr.y) + blo(xt.y) + blo(xq.y);
    const float s3 = bhi(xs.y) + bhi(xr.y) + bhi(xt.y) + bhi(xq.y);

    float v = fmaxf(s0, 0.f) * w.x + fmaxf(s1, 0.f) * w.y
            + fmaxf(s2, 0.f) * w.z + fmaxf(s3, 0.f) * w.w;
    v += __shfl_down(v, 8, 16);
    v += __shfl_down(v, 4, 16);
    v += __shfl_down(v, 2, 16);
    v += __shfl_down(v, 1, 16);

    if (g == 0) {
        const float alpha = 1.f / (1.f + __expf(-(v + w_alpha_b[0])));
        const int pos = atomicAdd(&cursor[obj], 1);
        metaA[pos] = make_int2(sub | (di << 17), rel);
        metaW[pos] = alpha;
    }
}

// ---------------------------------------------------------------------------
// K3: per-node aggregation, no atomics.
// ---------------------------------------------------------------------------
__device__ __forceinline__ void agg_step(
    int2 m, float al, int lane,
    const ushort_t* __restrict__ node_msg, const ushort_t* __restrict__ rel_msg,
    const ushort_t* __restrict__ dt_msg, float& a0, float& a1)
{
    const int sub = m.x & 0x1FFFF;
    const int di  = m.x >> 17;
    const int rel = m.y;
    const uint_t am = *(const uint_t*)(node_msg + (size_t)sub * 128 + 2 * lane);
    const uint_t bm = *(const uint_t*)(rel_msg  + (size_t)rel * 128 + 2 * lane);
    const uint_t tm = *(const uint_t*)(dt_msg   + (size_t)di  * 128 + 2 * lane);
    a0 += al * (blo(am) + blo(bm) + blo(tm));
    a1 += al * (bhi(am) + bhi(bm) + bhi(tm));
}

__global__ __launch_bounds__(256) void agg_kernel(
    const int* __restrict__ offs, const int2* __restrict__ metaA,
    const float* __restrict__ metaW,
    const ushort_t* __restrict__ node_msg, const ushort_t* __restrict__ rel_msg,
    const ushort_t* __restrict__ dt_msg, float* __restrict__ out)
{
    const int lane = threadIdx.x & 63;
    const int n    = blockIdx.x * 4 + (threadIdx.x >> 6);

    const int lo = offs[n], hi = offs[n + 1];
    float a0 = 0.f, a1 = 0.f;
    int j = lo;
    for (; j + 1 < hi; j += 2) {
        const int2 m0 = metaA[j];     const float w0 = metaW[j];
        const int2 m1 = metaA[j + 1]; const float w1 = metaW[j + 1];
        agg_step(m0, w0, lane, node_msg, rel_msg, dt_msg, a0, a1);
        agg_step(m1, w1, lane, node_msg, rel_msg, dt_msg, a0, a1);
    }
    if (j < hi)
        agg_step(metaA[j], metaW[j], lane, node_msg, rel_msg, dt_msg, a0, a1);

    ((float2*)(out + (size_t)n * OUT_DIM))[lane] = make_float2(a0, a1);
}

// ---------------------------------------------------------------------------
// Small-ws fallback kernels (tabs + single-pass atomic edge kernel).
// ---------------------------------------------------------------------------
__global__ __launch_bounds__(256) void node_tab_mfma(
    const float* __restrict__ hidden, const ushort_t* __restrict__ WTb,
    ushort_t* __restrict__ node_attn, ushort_t* __restrict__ node_msg)
{
    const int tid  = threadIdx.x;
    const int wid  = tid >> 6;
    const int lane = tid & 63;
    const int m16  = lane & 15;
    const int q    = lane >> 4;
    const int nb   = blockIdx.x * 64;
    const int row  = nb + wid * 16 + m16;
    const int rowc = row < N_NODE ? row : N_NODE - 1;

    v8s afr[4];
    #pragma unroll
    for (int c = 0; c < 4; ++c) {
        const float4 f0 = *(const float4*)(hidden + (size_t)rowc * 128 + 32 * c + 8 * q);
        const float4 f1 = *(const float4*)(hidden + (size_t)rowc * 128 + 32 * c + 8 * q + 4);
        v8s a;
        a[0] = (short)f2bu(f0.x); a[1] = (short)f2bu(f0.y);
        a[2] = (short)f2bu(f0.z); a[3] = (short)f2bu(f0.w);
        a[4] = (short)f2bu(f1.x); a[5] = (short)f2bu(f1.y);
        a[6] = (short)f2bu(f1.z); a[7] = (short)f2bu(f1.w);
        afr[c] = a;
    }
    #pragma unroll
    for (int t = 0; t < 12; ++t) {
        v4f acc = {0.f, 0.f, 0.f, 0.f};
        #pragma unroll
        for (int c = 0; c < 4; ++c) {
            const v8s bfr = *(const v8s*)(WTb + (size_t)(16 * t + m16) * 128 + 32 * c + 8 * q);
            acc = __builtin_amdgcn_mfma_f32_16x16x32_bf16(afr[c], bfr, acc, 0, 0, 0);
        }
        #pragma unroll
        for (int r = 0; r < 4; ++r) {
            const int node = nb + wid * 16 + 4 * q + r;
            if (node < N_NODE) {
                const int col = 16 * t + m16;
                if (col < 64) node_attn[(size_t)node * 64  + col]        = f2bu(acc[r]);
                else          node_msg [(size_t)node * 128 + (col - 64)] = f2bu(acc[r]);
            }
        }
    }
}

__global__ __launch_bounds__(128) void rel_tab_kernel(
    const float* __restrict__ rela, const float* __restrict__ Wr,
    const float* __restrict__ Wh,
    ushort_t* __restrict__ rel_attn, ushort_t* __restrict__ rel_msg)
{
    const int r = blockIdx.x, tid = threadIdx.x;
    __shared__ float h[IN_DIM];
    h[tid] = rela[(size_t)r * IN_DIM + tid];
    __syncthreads();
    if (tid < ATTN_DIM) {
        float a = 0.f;
        #pragma unroll 8
        for (int d = 0; d < IN_DIM; ++d) a += h[d] * Wr[d * ATTN_DIM + tid];
        rel_attn[(size_t)r * ATTN_DIM + tid] = f2bu(a);
    }
    float m = 0.f;
    #pragma unroll 8
    for (int d = 0; d < IN_DIM; ++d) m += h[d] * Wh[d * OUT_DIM + tid];
    rel_msg[(size_t)r * OUT_DIM + tid] = f2bu(m);
}

__global__ __launch_bounds__(128) void dt_tab_kernel(
    const float* __restrict__ wt1, const float* __restrict__ bt1,
    const float* __restrict__ wt2, const float* __restrict__ bt2,
    const float* __restrict__ Wtau, const float* __restrict__ Wh,
    ushort_t* __restrict__ dt_attn, ushort_t* __restrict__ dt_msg)
{
    const int i = blockIdx.x, tid = threadIdx.x;
    const float dt = (float)(i - 365);
    __shared__ float h[IN_DIM];
    h[tid] = wt1[tid] * dt + bt1[tid] + sinf(wt2[tid] * dt + bt2[tid]);
    __syncthreads();
    if (tid < ATTN_DIM) {
        float a = 0.f;
        #pragma unroll 8
        for (int d = 0; d < IN_DIM; ++d) a += h[d] * Wtau[d * ATTN_DIM + tid];
        dt_attn[(size_t)i * ATTN_DIM + tid] = f2bu(a);
    }
    float m = 0.f;
    #pragma unroll 8
    for (int d = 0; d < IN_DIM; ++d) m += h[d] * Wh[d * OUT_DIM + tid];
    dt_msg[(size_t)i * OUT_DIM + tid] = f2bu(m);
}

__global__ __launch_bounds__(64) void qr_tab_kernel(
    const float* __restrict__ rela, const int* __restrict__ q_rel,
    const float* __restrict__ W, const float* __restrict__ bias,
    const int* __restrict__ flag, ushort_t* __restrict__ Xqr)
{
    const int q = blockIdx.x, lane = threadIdx.x;
    const int i64 = flag[0];
    const int rel = clampi(q_rel[i64 ? 2 * q : q], 0, N_RELV - 1);
    __shared__ float h[IN_DIM];
    const float2 v = ((const float2*)(rela + (size_t)rel * IN_DIM))[lane];
    h[2 * lane] = v.x; h[2 * lane + 1] = v.y;
    __syncthreads();
    float acc = bias[lane];
    #pragma unroll 8
    for (int d = 0; d < IN_DIM; ++d) acc += h[d] * W[d * ATTN_DIM + lane];
    Xqr[(size_t)q * ATTN_DIM + lane] = f2bu(acc);
}

__global__ __launch_bounds__(256) void edge_atomic_kernel(
    const int* __restrict__ edges, const int* __restrict__ q_tau,
    const ushort_t* __restrict__ node_attn, const ushort_t* __restrict__ node_msg,
    const ushort_t* __restrict__ rel_attn,  const ushort_t* __restrict__ rel_msg,
    const ushort_t* __restrict__ dt_attn,   const ushort_t* __restrict__ dt_msg,
    const ushort_t* __restrict__ Xqr,
    const float* __restrict__ w_alpha_W, const float* __restrict__ w_alpha_b,
    const int* __restrict__ flag, float* __restrict__ out)
{
    const int lane = threadIdx.x & 63;
    const int e    = blockIdx.x * 4 + (threadIdx.x >> 6);
    const int i64  = flag[0];

    int r, rel, tau, sub, obj;
    parse_edge(edges, e, i64, r, rel, tau, sub, obj);
    const int tq = q_tau[i64 ? 2 * r : r];
    if (tau < 0) tau = tq;
    const int di = clampi(tau - tq + 365, 0, N_DT - 1);

    const float xs = bu2f(node_attn[(size_t)sub * ATTN_DIM + lane]);
    const float xr = bu2f(rel_attn[(size_t)rel * ATTN_DIM + lane]);
    const float xt = bu2f(dt_attn[(size_t)di  * ATTN_DIM + lane]);
    const float xq = bu2f(Xqr[(size_t)r * ATTN_DIM + lane]);

    float v = fmaxf(xs + xr + xq + xt, 0.f) * w_alpha_W[lane];
    #pragma unroll
    for (int off = 32; off > 0; off >>= 1)
        v += __shfl_down(v, off, 64);
    v = __shfl(v, 0, 64);
    const float alpha = 1.f / (1.f + __expf(-(v + w_alpha_b[0])));

    const uint_t am = *(const uint_t*)(node_msg + (size_t)sub * 128 + 2 * lane);
    const uint_t bm = *(const uint_t*)(rel_msg  + (size_t)rel * 128 + 2 * lane);
    const uint_t tm = *(const uint_t*)(dt_msg   + (size_t)di  * 128 + 2 * lane);
    const float mx = blo(am) + blo(bm) + blo(tm);
    const float my = bhi(am) + bhi(bm) + bhi(tm);

    float* dst = out + (size_t)obj * OUT_DIM;
    atomicAdd(dst + 2 * lane,     alpha * mx);
    atomicAdd(dst + 2 * lane + 1, alpha * my);
}

// ===========================================================================
extern "C" void kernel_launch(void* const* d_in, const int* in_sizes, int n_in,
                              void* d_out, int out_size, void* d_ws, size_t ws_size,
                              hipStream_t stream)
{
    const int*   q_rel  = (const int*)d_in[1];
    const int*   q_tau  = (const int*)d_in[2];
    const float* hidden = (const float*)d_in[3];
    const int*   edges  = (const int*)d_in[4];
    const float* rela   = (const float*)d_in[7];
    const float* Ws     = (const float*)d_in[8];
    const float* Wr     = (const float*)d_in[9];
    const float* WqrW   = (const float*)d_in[10];
    const float* Wqrb   = (const float*)d_in[11];
    const float* Wtau   = (const float*)d_in[12];
    const float* waW    = (const float*)d_in[13];
    const float* wab    = (const float*)d_in[14];
    const float* Wh     = (const float*)d_in[15];
    const float* wt1    = (const float*)d_in[16];
    const float* bt1    = (const float*)d_in[17];
    const float* wt2    = (const float*)d_in[18];
    const float* bt2    = (const float*)d_in[19];
    float* out = (float*)d_out;

    // --- workspace carve (256-B aligned chunks) ---
    char* p = (char*)d_ws;
    size_t off = 0;
    auto carve = [&](size_t bytes) {
        char* q = p + off;
        off = (off + bytes + 255) & ~(size_t)255;
        return q;
    };
    int*      flag      = (int*)     carve(64);
    int*      bar       = (int*)     carve(64);
    ushort_t* WTb       = (ushort_t*)carve((size_t)192 * 128 * 2);
    ushort_t* XqrB      = (ushort_t*)carve((size_t)N_QUERY * ATTN_DIM * 2);
    ushort_t* rel_attn  = (ushort_t*)carve((size_t)N_RELV * ATTN_DIM * 2);
    ushort_t* rel_msg   = (ushort_t*)carve((size_t)N_RELV * OUT_DIM * 2);
    ushort_t* dt_attn   = (ushort_t*)carve((size_t)N_DT * ATTN_DIM * 2);
    ushort_t* dt_msg    = (ushort_t*)carve((size_t)N_DT * OUT_DIM * 2);
    ushort_t* node_attn = (ushort_t*)carve((size_t)N_NODE * ATTN_DIM * 2);
    ushort_t* node_msg  = (ushort_t*)carve((size_t)N_NODE * OUT_DIM * 2);
    int*      deg       = (int*)     carve((size_t)N_NODE * 4);
    int*      offs      = (int*)     carve(((size_t)N_NODE + 1) * 4);
    int*      cursor    = (int*)     carve((size_t)N_NODE * 4);
    int*      chunksum  = (int*)     carve(256 * 4);
    int*      chunkbase = (int*)     carve(256 * 4);
    int2*     metaA     = (int2*)    carve((size_t)N_EDGE * 8);
    float*    metaW     = (float*)   carve((size_t)N_EDGE * 4);
    const size_t need_csr = off;

    init_kernel<<<1, 256, 0, stream>>>(edges, Ws, Wh, flag, bar, WTb, deg);

    if (ws_size >= need_csr) {
        MegaArgs ma;
        ma.edges = edges; ma.q_rel = q_rel; ma.q_tau = q_tau;
        ma.hidden = hidden; ma.rela = rela;
        ma.Wr = Wr; ma.WqrW = WqrW; ma.Wqrb = Wqrb;
        ma.Wtau = Wtau; ma.Wh = Wh;
        ma.wt1 = wt1; ma.bt1 = bt1; ma.wt2 = wt2; ma.bt2 = bt2;
        ma.flag = flag; ma.bar = bar;
        ma.WTb = WTb; ma.XqrB = XqrB;
        ma.rel_attn = rel_attn; ma.rel_msg = rel_msg;
        ma.dt_attn = dt_attn;   ma.dt_msg = dt_msg;
        ma.node_attn = node_attn; ma.node_msg = node_msg;
        ma.deg = deg; ma.offs = offs; ma.cursor = cursor;
        ma.chunksum = chunksum; ma.chunkbase = chunkbase;

        mega_front  <<<MEGA_NB,     256, 0, stream>>>(ma);
        alpha_kernel<<<N_EDGE / 16, 256, 0, stream>>>(edges, q_tau, node_attn,
                                                      rel_attn, dt_attn, XqrB,
                                                      waW, wab, flag, cursor,
                                                      metaA, metaW);
        agg_kernel  <<<N_NODE / 4,  256, 0, stream>>>(offs, metaA, metaW,
                                                      node_msg, rel_msg, dt_msg, out);
    } else {
        // tiny-ws fallback: tab kernels + atomic single-pass
        node_tab_mfma<<<(N_NODE + 63) / 64, 256, 0, stream>>>(hidden, WTb,
                                                              node_attn, node_msg);
        rel_tab_kernel<<<N_RELV, 128, 0, stream>>>(rela, Wr, Wh, rel_attn, rel_msg);
        dt_tab_kernel <<<N_DT,   128, 0, stream>>>(wt1, bt1, wt2, bt2, Wtau, Wh,
                                                   dt_attn, dt_msg);
        qr_tab_kernel <<<N_QUERY, 64, 0, stream>>>(rela, q_rel, WqrW, Wqrb, flag, XqrB);
        (void)hipMemsetAsync(out, 0, (size_t)out_size * sizeof(float), stream);
        edge_atomic_kernel<<<N_EDGE / 4, 256, 0, stream>>>(edges, q_tau,
                                                           node_attn, node_msg,
                                                           rel_attn, rel_msg,
                                                           dt_attn, dt_msg, XqrB,
                                                           waW, wab, flag, out);
    }
}

// Round 11
// 313.323 us; speedup vs baseline: 2.8626x; 2.8626x over previous
//
#include <hip/hip_runtime.h>

#define IN_DIM   128
#define OUT_DIM  128
#define ATTN_DIM 64
#define N_RELV   401
#define N_NODE   50000
#define N_EDGE   500000
#define N_QUERY  64
#define N_DT     731
#define TAB_NB   782      // ceil(50000/64) node-MFMA units

typedef unsigned short ushort_t;
typedef unsigned int   uint_t;
typedef __attribute__((ext_vector_type(8))) short v8s;   // 8 bf16 (4 VGPRs)
typedef __attribute__((ext_vector_type(4))) float v4f;

__device__ __forceinline__ int clampi(int v, int lo, int hi) {
    return v < lo ? lo : (v > hi ? hi : v);
}
__device__ __forceinline__ float bu2f(ushort_t u) {
    union { uint_t i; float f; } v; v.i = ((uint_t)u) << 16; return v.f;
}
__device__ __forceinline__ float blo(uint_t u) { return bu2f((ushort_t)(u & 0xffff)); }
__device__ __forceinline__ float bhi(uint_t u) { return bu2f((ushort_t)(u >> 16)); }
__device__ __forceinline__ ushort_t f2bu(float f) {   // RNE, finite inputs
    union { float f; uint_t i; } v; v.f = f;
    const uint_t x = v.i;
    return (ushort_t)((x + 0x7fffu + ((x >> 16) & 1u)) >> 16);
}

__device__ __forceinline__ void parse_edge(const int* __restrict__ edges, int e,
                                           int i64, int& r, int& rel, int& tau,
                                           int& sub, int& obj) {
    if (i64) {
        const int* E = edges + (size_t)e * 14;
        r = E[0]; rel = E[4]; tau = E[8]; sub = E[10]; obj = E[12];
    } else {
        const int* E = edges + (size_t)e * 7;
        r = E[0]; rel = E[2]; tau = E[4]; sub = E[5]; obj = E[6];
    }
    r   = clampi(r,   0, N_QUERY - 1);
    rel = clampi(rel, 0, N_RELV - 1);
    sub = clampi(sub, 0, N_NODE - 1);
    obj = clampi(obj, 0, N_NODE - 1);
}

// ---------------------------------------------------------------------------
// K0: init — detect int width, build WTb, zero deg.
// ---------------------------------------------------------------------------
__global__ __launch_bounds__(256) void init_kernel(
    const int* __restrict__ edges, const float* __restrict__ Ws,
    const float* __restrict__ Wh,
    int* __restrict__ flag, ushort_t* __restrict__ WTb, int* __restrict__ deg)
{
    const int tid = threadIdx.x;
    __shared__ int bad;
    if (tid == 0) bad = 0;
    __syncthreads();
    for (int i = tid; i < 1000; i += 256) {
        const int w = edges[2 * i + 1];
        if (w != 0 && w != -1) bad = 1;
    }
    __syncthreads();
    if (tid == 0) flag[0] = (bad == 0) ? 1 : 0;

    for (int i = tid; i < 192 * 128; i += 256) {
        const int n = i >> 7, k = i & 127;
        const float w = (n < 64) ? Ws[k * 64 + n] : Wh[k * 128 + (n - 64)];
        WTb[i] = f2bu(w);
    }
    for (int i = tid; i < N_NODE; i += 256) deg[i] = 0;
}

// ---------------------------------------------------------------------------
// K1: fused tabs + histogram — five independent jobs, grid-stride, NO sync.
// ---------------------------------------------------------------------------
struct TabArgs {
    const int*   edges; const int* q_rel;
    const float* hidden; const float* rela;
    const float* Wr; const float* WqrW; const float* Wqrb;
    const float* Wtau; const float* Wh;
    const float* wt1; const float* bt1; const float* wt2; const float* bt2;
    const int* flag;
    const ushort_t* WTb;
    ushort_t* XqrB;
    ushort_t* rel_attn; ushort_t* rel_msg;
    ushort_t* dt_attn;  ushort_t* dt_msg;
    ushort_t* node_attn; ushort_t* node_msg;
    int* deg;
};

__global__ __launch_bounds__(256) void tabs_hist_kernel(TabArgs a)
{
    const int nb  = gridDim.x;
    const int bid = blockIdx.x;
    const int tid = threadIdx.x;

    __shared__ float hbuf[4][IN_DIM];

    {   // node MFMA projection (LDS-free), 782 units of 64 rows
        const int wid  = tid >> 6;
        const int lane = tid & 63;
        const int m16  = lane & 15;
        const int q    = lane >> 4;
        for (int u = bid; u < (N_NODE + 63) / 64; u += nb) {
            const int nbase = u * 64;
            const int row   = nbase + wid * 16 + m16;
            const int rowc  = row < N_NODE ? row : N_NODE - 1;
            v8s afr[4];
            #pragma unroll
            for (int c = 0; c < 4; ++c) {
                const float4 f0 = *(const float4*)(a.hidden + (size_t)rowc * 128 + 32 * c + 8 * q);
                const float4 f1 = *(const float4*)(a.hidden + (size_t)rowc * 128 + 32 * c + 8 * q + 4);
                v8s v;
                v[0] = (short)f2bu(f0.x); v[1] = (short)f2bu(f0.y);
                v[2] = (short)f2bu(f0.z); v[3] = (short)f2bu(f0.w);
                v[4] = (short)f2bu(f1.x); v[5] = (short)f2bu(f1.y);
                v[6] = (short)f2bu(f1.z); v[7] = (short)f2bu(f1.w);
                afr[c] = v;
            }
            #pragma unroll
            for (int t = 0; t < 12; ++t) {
                v4f acc = {0.f, 0.f, 0.f, 0.f};
                #pragma unroll
                for (int c = 0; c < 4; ++c) {
                    const v8s bfr = *(const v8s*)(a.WTb + (size_t)(16 * t + m16) * 128 + 32 * c + 8 * q);
                    acc = __builtin_amdgcn_mfma_f32_16x16x32_bf16(afr[c], bfr, acc, 0, 0, 0);
                }
                #pragma unroll
                for (int r = 0; r < 4; ++r) {
                    const int node = nbase + wid * 16 + 4 * q + r;
                    if (node < N_NODE) {
                        const int col = 16 * t + m16;
                        if (col < 64) a.node_attn[(size_t)node * 64  + col]        = f2bu(acc[r]);
                        else          a.node_msg [(size_t)node * 128 + (col - 64)] = f2bu(acc[r]);
                    }
                }
            }
        }
    }
    {   // rel tabs, 2 per block
        const int half = tid >> 7, t = tid & 127;
        for (int u = bid; u < (N_RELV + 1) / 2; u += nb) {
            const int r = 2 * u + half;
            if (r < N_RELV) hbuf[half][t] = a.rela[(size_t)r * IN_DIM + t];
            __syncthreads();
            if (r < N_RELV) {
                if (t < ATTN_DIM) {
                    float x = 0.f;
                    #pragma unroll 8
                    for (int d = 0; d < IN_DIM; ++d) x += hbuf[half][d] * a.Wr[d * ATTN_DIM + t];
                    a.rel_attn[(size_t)r * ATTN_DIM + t] = f2bu(x);
                }
                float m = 0.f;
                #pragma unroll 8
                for (int d = 0; d < IN_DIM; ++d) m += hbuf[half][d] * a.Wh[d * OUT_DIM + t];
                a.rel_msg[(size_t)r * OUT_DIM + t] = f2bu(m);
            }
            __syncthreads();
        }
    }
    {   // dt tabs, 2 per block
        const int half = tid >> 7, t = tid & 127;
        for (int u = bid; u < (N_DT + 1) / 2; u += nb) {
            const int i = 2 * u + half;
            if (i < N_DT) {
                const float dt = (float)(i - 365);
                hbuf[half][t] = a.wt1[t] * dt + a.bt1[t] + sinf(a.wt2[t] * dt + a.bt2[t]);
            }
            __syncthreads();
            if (i < N_DT) {
                if (t < ATTN_DIM) {
                    float x = 0.f;
                    #pragma unroll 8
                    for (int d = 0; d < IN_DIM; ++d) x += hbuf[half][d] * a.Wtau[d * ATTN_DIM + t];
                    a.dt_attn[(size_t)i * ATTN_DIM + t] = f2bu(x);
                }
                float m = 0.f;
                #pragma unroll 8
                for (int d = 0; d < IN_DIM; ++d) m += hbuf[half][d] * a.Wh[d * OUT_DIM + t];
                a.dt_msg[(size_t)i * OUT_DIM + t] = f2bu(m);
            }
            __syncthreads();
        }
    }
    {   // qr tab, 4 per block (16 units)
        const int sq = tid >> 6, lane = tid & 63;
        const int i64 = a.flag[0];
        for (int u = bid; u < N_QUERY / 4; u += nb) {
            const int qq  = 4 * u + sq;
            const int rel = clampi(a.q_rel[i64 ? 2 * qq : qq], 0, N_RELV - 1);
            const float2 v = ((const float2*)(a.rela + (size_t)rel * IN_DIM))[lane];
            hbuf[sq][2 * lane] = v.x; hbuf[sq][2 * lane + 1] = v.y;
            __syncthreads();
            float acc = a.Wqrb[lane];
            #pragma unroll 8
            for (int d = 0; d < IN_DIM; ++d) acc += hbuf[sq][d] * a.WqrW[d * ATTN_DIM + lane];
            a.XqrB[(size_t)qq * ATTN_DIM + lane] = f2bu(acc);
            __syncthreads();
        }
    }
    {   // degree histogram
        const int i64 = a.flag[0];
        const int gsz = nb * 256;
        for (int e = bid * 256 + tid; e < N_EDGE; e += gsz) {
            int obj = i64 ? a.edges[(size_t)e * 14 + 12] : a.edges[(size_t)e * 7 + 6];
            obj = clampi(obj, 0, N_NODE - 1);
            atomicAdd(&a.deg[obj], 1);
        }
    }
}

// ---------------------------------------------------------------------------
// K2: single-block exclusive scan of deg -> offs, cursor. 1024 threads,
// per-wave shfl scan + wave-sum scan + running carry. 49 iterations.
// ---------------------------------------------------------------------------
__global__ __launch_bounds__(1024) void scan_kernel(
    const int* __restrict__ deg, int* __restrict__ offs, int* __restrict__ cursor)
{
    const int tid  = threadIdx.x;
    const int lane = tid & 63;
    const int wid  = tid >> 6;        // 16 waves
    __shared__ int wsum[16];
    __shared__ int carry;
    if (tid == 0) carry = 0;
    __syncthreads();

    for (int base = 0; base < N_NODE; base += 1024) {
        const int i = base + tid;
        const int v = (i < N_NODE) ? deg[i] : 0;

        // inclusive scan within wave
        int acc = v;
        #pragma unroll
        for (int o = 1; o < 64; o <<= 1) {
            const int t = __shfl_up(acc, o, 64);
            if (lane >= o) acc += t;
        }
        if (lane == 63) wsum[wid] = acc;
        __syncthreads();

        // scan the 16 wave sums (wave 0, lanes 0..15)
        if (wid == 0 && lane < 16) {
            int wv = wsum[lane];
            #pragma unroll
            for (int o = 1; o < 16; o <<= 1) {
                const int t = __shfl_up(wv, o, 64);
                if (lane >= o) wv += t;
            }
            wsum[lane] = wv;          // inclusive
        }
        __syncthreads();

        const int wbase = (wid > 0) ? wsum[wid - 1] : 0;
        const int excl  = acc - v + wbase + carry;
        if (i < N_NODE) { offs[i] = excl; cursor[i] = excl; }
        __syncthreads();              // everyone has read carry & wsum

        if (tid == 0) carry += wsum[15];
        __syncthreads();
    }
    if (tid == 0) offs[N_NODE] = N_EDGE;
}

// ---------------------------------------------------------------------------
// K3: per-edge alpha. 16 lanes per edge (4 edges/wave).
// meta.x = sub | (di<<17), meta.y = rel, metaW = alpha.
// ---------------------------------------------------------------------------
__global__ __launch_bounds__(256) void alpha_kernel(
    const int* __restrict__ edges, const int* __restrict__ q_tau,
    const ushort_t* __restrict__ node_attn, const ushort_t* __restrict__ rel_attn,
    const ushort_t* __restrict__ dt_attn,  const ushort_t* __restrict__ Xqr,
    const float* __restrict__ w_alpha_W, const float* __restrict__ w_alpha_b,
    const int* __restrict__ flag, int* __restrict__ cursor,
    int2* __restrict__ metaA, float* __restrict__ metaW)
{
    const int g   = threadIdx.x & 15;
    const int e   = blockIdx.x * 16 + (threadIdx.x >> 4);
    const int i64 = flag[0];

    int r, rel, tau, sub, obj;
    parse_edge(edges, e, i64, r, rel, tau, sub, obj);
    const int tq = q_tau[i64 ? 2 * r : r];
    if (tau < 0) tau = tq;
    const int di = clampi(tau - tq + 365, 0, N_DT - 1);

    const uint2 xs = *(const uint2*)(node_attn + (size_t)sub * ATTN_DIM + 4 * g);
    const uint2 xr = *(const uint2*)(rel_attn + (size_t)rel * ATTN_DIM + 4 * g);
    const uint2 xt = *(const uint2*)(dt_attn  + (size_t)di  * ATTN_DIM + 4 * g);
    const uint2 xq = *(const uint2*)(Xqr      + (size_t)r   * ATTN_DIM + 4 * g);
    const float4 w = *(const float4*)(w_alpha_W + 4 * g);

    const float s0 = blo(xs.x) + blo(xr.x) + blo(xt.x) + blo(xq.x);
    const float s1 = bhi(xs.x) + bhi(xr.x) + bhi(xt.x) + bhi(xq.x);
    const float s2 = blo(xs.y) + blo(xr.y) + blo(xt.y) + blo(xq.y);
    const float s3 = bhi(xs.y) + bhi(xr.y) + bhi(xt.y) + bhi(xq.y);

    float v = fmaxf(s0, 0.f) * w.x + fmaxf(s1, 0.f) * w.y
            + fmaxf(s2, 0.f) * w.z + fmaxf(s3, 0.f) * w.w;
    v += __shfl_down(v, 8, 16);
    v += __shfl_down(v, 4, 16);
    v += __shfl_down(v, 2, 16);
    v += __shfl_down(v, 1, 16);

    if (g == 0) {
        const float alpha = 1.f / (1.f + __expf(-(v + w_alpha_b[0])));
        const int pos = atomicAdd(&cursor[obj], 1);
        metaA[pos] = make_int2(sub | (di << 17), rel);
        metaW[pos] = alpha;
    }
}

// ---------------------------------------------------------------------------
// K4: per-node aggregation, no atomics.
// ---------------------------------------------------------------------------
__device__ __forceinline__ void agg_step(
    int2 m, float al, int lane,
    const ushort_t* __restrict__ node_msg, const ushort_t* __restrict__ rel_msg,
    const ushort_t* __restrict__ dt_msg, float& a0, float& a1)
{
    const int sub = m.x & 0x1FFFF;
    const int di  = m.x >> 17;
    const int rel = m.y;
    const uint_t am = *(const uint_t*)(node_msg + (size_t)sub * 128 + 2 * lane);
    const uint_t bm = *(const uint_t*)(rel_msg  + (size_t)rel * 128 + 2 * lane);
    const uint_t tm = *(const uint_t*)(dt_msg   + (size_t)di  * 128 + 2 * lane);
    a0 += al * (blo(am) + blo(bm) + blo(tm));
    a1 += al * (bhi(am) + bhi(bm) + bhi(tm));
}

__global__ __launch_bounds__(256) void agg_kernel(
    const int* __restrict__ offs, const int2* __restrict__ metaA,
    const float* __restrict__ metaW,
    const ushort_t* __restrict__ node_msg, const ushort_t* __restrict__ rel_msg,
    const ushort_t* __restrict__ dt_msg, float* __restrict__ out)
{
    const int lane = threadIdx.x & 63;
    const int n    = blockIdx.x * 4 + (threadIdx.x >> 6);

    const int lo = offs[n], hi = offs[n + 1];
    float a0 = 0.f, a1 = 0.f;
    int j = lo;
    for (; j + 1 < hi; j += 2) {
        const int2 m0 = metaA[j];     const float w0 = metaW[j];
        const int2 m1 = metaA[j + 1]; const float w1 = metaW[j + 1];
        agg_step(m0, w0, lane, node_msg, rel_msg, dt_msg, a0, a1);
        agg_step(m1, w1, lane, node_msg, rel_msg, dt_msg, a0, a1);
    }
    if (j < hi)
        agg_step(metaA[j], metaW[j], lane, node_msg, rel_msg, dt_msg, a0, a1);

    ((float2*)(out + (size_t)n * OUT_DIM))[lane] = make_float2(a0, a1);
}

// ---------------------------------------------------------------------------
// Small-ws fallback: single-pass atomic edge kernel (uses tabs from K1).
// ---------------------------------------------------------------------------
__global__ __launch_bounds__(256) void edge_atomic_kernel(
    const int* __restrict__ edges, const int* __restrict__ q_tau,
    const ushort_t* __restrict__ node_attn, const ushort_t* __restrict__ node_msg,
    const ushort_t* __restrict__ rel_attn,  const ushort_t* __restrict__ rel_msg,
    const ushort_t* __restrict__ dt_attn,   const ushort_t* __restrict__ dt_msg,
    const ushort_t* __restrict__ Xqr,
    const float* __restrict__ w_alpha_W, const float* __restrict__ w_alpha_b,
    const int* __restrict__ flag, float* __restrict__ out)
{
    const int lane = threadIdx.x & 63;
    const int e    = blockIdx.x * 4 + (threadIdx.x >> 6);
    const int i64  = flag[0];

    int r, rel, tau, sub, obj;
    parse_edge(edges, e, i64, r, rel, tau, sub, obj);
    const int tq = q_tau[i64 ? 2 * r : r];
    if (tau < 0) tau = tq;
    const int di = clampi(tau - tq + 365, 0, N_DT - 1);

    const float xs = bu2f(node_attn[(size_t)sub * ATTN_DIM + lane]);
    const float xr = bu2f(rel_attn[(size_t)rel * ATTN_DIM + lane]);
    const float xt = bu2f(dt_attn[(size_t)di  * ATTN_DIM + lane]);
    const float xq = bu2f(Xqr[(size_t)r * ATTN_DIM + lane]);

    float v = fmaxf(xs + xr + xq + xt, 0.f) * w_alpha_W[lane];
    #pragma unroll
    for (int off = 32; off > 0; off >>= 1)
        v += __shfl_down(v, off, 64);
    v = __shfl(v, 0, 64);
    const float alpha = 1.f / (1.f + __expf(-(v + w_alpha_b[0])));

    const uint_t am = *(const uint_t*)(node_msg + (size_t)sub * 128 + 2 * lane);
    const uint_t bm = *(const uint_t*)(rel_msg  + (size_t)rel * 128 + 2 * lane);
    const uint_t tm = *(const uint_t*)(dt_msg   + (size_t)di  * 128 + 2 * lane);
    const float mx = blo(am) + blo(bm) + blo(tm);
    const float my = bhi(am) + bhi(bm) + bhi(tm);

    float* dst = out + (size_t)obj * OUT_DIM;
    atomicAdd(dst + 2 * lane,     alpha * mx);
    atomicAdd(dst + 2 * lane + 1, alpha * my);
}

// ===========================================================================
extern "C" void kernel_launch(void* const* d_in, const int* in_sizes, int n_in,
                              void* d_out, int out_size, void* d_ws, size_t ws_size,
                              hipStream_t stream)
{
    const int*   q_rel  = (const int*)d_in[1];
    const int*   q_tau  = (const int*)d_in[2];
    const float* hidden = (const float*)d_in[3];
    const int*   edges  = (const int*)d_in[4];
    const float* rela   = (const float*)d_in[7];
    const float* Ws     = (const float*)d_in[8];
    const float* Wr     = (const float*)d_in[9];
    const float* WqrW   = (const float*)d_in[10];
    const float* Wqrb   = (const float*)d_in[11];
    const float* Wtau   = (const float*)d_in[12];
    const float* waW    = (const float*)d_in[13];
    const float* wab    = (const float*)d_in[14];
    const float* Wh     = (const float*)d_in[15];
    const float* wt1    = (const float*)d_in[16];
    const float* bt1    = (const float*)d_in[17];
    const float* wt2    = (const float*)d_in[18];
    const float* bt2    = (const float*)d_in[19];
    float* out = (float*)d_out;

    // --- workspace carve (256-B aligned chunks) ---
    char* p = (char*)d_ws;
    size_t off = 0;
    auto carve = [&](size_t bytes) {
        char* q = p + off;
        off = (off + bytes + 255) & ~(size_t)255;
        return q;
    };
    int*      flag      = (int*)     carve(64);
    ushort_t* WTb       = (ushort_t*)carve((size_t)192 * 128 * 2);
    ushort_t* XqrB      = (ushort_t*)carve((size_t)N_QUERY * ATTN_DIM * 2);
    ushort_t* rel_attn  = (ushort_t*)carve((size_t)N_RELV * ATTN_DIM * 2);
    ushort_t* rel_msg   = (ushort_t*)carve((size_t)N_RELV * OUT_DIM * 2);
    ushort_t* dt_attn   = (ushort_t*)carve((size_t)N_DT * ATTN_DIM * 2);
    ushort_t* dt_msg    = (ushort_t*)carve((size_t)N_DT * OUT_DIM * 2);
    ushort_t* node_attn = (ushort_t*)carve((size_t)N_NODE * ATTN_DIM * 2);
    ushort_t* node_msg  = (ushort_t*)carve((size_t)N_NODE * OUT_DIM * 2);
    int*      deg       = (int*)     carve((size_t)N_NODE * 4);
    int*      offs      = (int*)     carve(((size_t)N_NODE + 1) * 4);
    int*      cursor    = (int*)     carve((size_t)N_NODE * 4);
    int2*     metaA     = (int2*)    carve((size_t)N_EDGE * 8);
    float*    metaW     = (float*)   carve((size_t)N_EDGE * 4);
    const size_t need_csr = off;

    init_kernel<<<1, 256, 0, stream>>>(edges, Ws, Wh, flag, WTb, deg);

    TabArgs ta;
    ta.edges = edges; ta.q_rel = q_rel;
    ta.hidden = hidden; ta.rela = rela;
    ta.Wr = Wr; ta.WqrW = WqrW; ta.Wqrb = Wqrb;
    ta.Wtau = Wtau; ta.Wh = Wh;
    ta.wt1 = wt1; ta.bt1 = bt1; ta.wt2 = wt2; ta.bt2 = bt2;
    ta.flag = flag; ta.WTb = WTb; ta.XqrB = XqrB;
    ta.rel_attn = rel_attn; ta.rel_msg = rel_msg;
    ta.dt_attn = dt_attn;   ta.dt_msg = dt_msg;
    ta.node_attn = node_attn; ta.node_msg = node_msg;
    ta.deg = deg;

    tabs_hist_kernel<<<TAB_NB, 256, 0, stream>>>(ta);

    if (ws_size >= need_csr) {
        scan_kernel <<<1, 1024, 0, stream>>>(deg, offs, cursor);
        alpha_kernel<<<N_EDGE / 16, 256, 0, stream>>>(edges, q_tau, node_attn,
                                                      rel_attn, dt_attn, XqrB,
                                                      waW, wab, flag, cursor,
                                                      metaA, metaW);
        agg_kernel  <<<N_NODE / 4,  256, 0, stream>>>(offs, metaA, metaW,
                                                      node_msg, rel_msg, dt_msg, out);
    } else {
        (void)hipMemsetAsync(out, 0, (size_t)out_size * sizeof(float), stream);
        edge_atomic_kernel<<<N_EDGE / 4, 256, 0, stream>>>(edges, q_tau,
                                                           node_attn, node_msg,
                                                           rel_attn, rel_msg,
                                                           dt_attn, dt_msg, XqrB,
                                                           waW, wab, flag, out);
    }
}

// Round 12
// 293.199 us; speedup vs baseline: 3.0590x; 1.0686x over previous
//
#include <hip/hip_runtime.h>

#define IN_DIM   128
#define OUT_DIM  128
#define ATTN_DIM 64
#define N_RELV   401
#define N_NODE   50000
#define N_EDGE   500000
#define N_QUERY  64
#define N_DT     731
#define TAB_NB   782      // ceil(50000/64) node-MFMA units
#define NCH      196      // ceil(50000/256) scan chunks
#define STG      200      // LDS stage row stride in b16 (400 B: 16B-aligned, conflict-free)

typedef unsigned short ushort_t;
typedef unsigned int   uint_t;
typedef __attribute__((ext_vector_type(8))) short v8s;   // 8 bf16 (4 VGPRs)
typedef __attribute__((ext_vector_type(4))) float v4f;

__device__ __forceinline__ int clampi(int v, int lo, int hi) {
    return v < lo ? lo : (v > hi ? hi : v);
}
__device__ __forceinline__ float bu2f(ushort_t u) {
    union { uint_t i; float f; } v; v.i = ((uint_t)u) << 16; return v.f;
}
__device__ __forceinline__ float blo(uint_t u) { return bu2f((ushort_t)(u & 0xffff)); }
__device__ __forceinline__ float bhi(uint_t u) { return bu2f((ushort_t)(u >> 16)); }
__device__ __forceinline__ ushort_t f2bu(float f) {   // RNE, finite inputs
    union { float f; uint_t i; } v; v.f = f;
    const uint_t x = v.i;
    return (ushort_t)((x + 0x7fffu + ((x >> 16) & 1u)) >> 16);
}

__device__ __forceinline__ void parse_edge(const int* __restrict__ edges, int e,
                                           int i64, int& r, int& rel, int& tau,
                                           int& sub, int& obj) {
    if (i64) {
        const int* E = edges + (size_t)e * 14;
        r = E[0]; rel = E[4]; tau = E[8]; sub = E[10]; obj = E[12];
    } else {
        const int* E = edges + (size_t)e * 7;
        r = E[0]; rel = E[2]; tau = E[4]; sub = E[5]; obj = E[6];
    }
    r   = clampi(r,   0, N_QUERY - 1);
    rel = clampi(rel, 0, N_RELV - 1);
    sub = clampi(sub, 0, N_NODE - 1);
    obj = clampi(obj, 0, N_NODE - 1);
}

// ---------------------------------------------------------------------------
// K0: init — detect int width, build WTb, zero deg.
// ---------------------------------------------------------------------------
__global__ __launch_bounds__(256) void init_kernel(
    const int* __restrict__ edges, const float* __restrict__ Ws,
    const float* __restrict__ Wh,
    int* __restrict__ flag, ushort_t* __restrict__ WTb, int* __restrict__ deg)
{
    const int tid = threadIdx.x;
    __shared__ int bad;
    if (tid == 0) bad = 0;
    __syncthreads();
    for (int i = tid; i < 1000; i += 256) {
        const int w = edges[2 * i + 1];
        if (w != 0 && w != -1) bad = 1;
    }
    __syncthreads();
    if (tid == 0) flag[0] = (bad == 0) ? 1 : 0;

    for (int i = tid; i < 192 * 128; i += 256) {
        const int n = i >> 7, k = i & 127;
        const float w = (n < 64) ? Ws[k * 64 + n] : Wh[k * 128 + (n - 64)];
        WTb[i] = f2bu(w);
    }
    for (int i = tid; i < N_NODE; i += 256) deg[i] = 0;
}

// ---------------------------------------------------------------------------
// K1: fused tabs + histogram — independent jobs, grid-stride, no grid sync.
// Node MFMA output staged in LDS then stored as coalesced uint4.
// ---------------------------------------------------------------------------
struct TabArgs {
    const int*   edges; const int* q_rel;
    const float* hidden; const float* rela;
    const float* Wr; const float* WqrW; const float* Wqrb;
    const float* Wtau; const float* Wh;
    const float* wt1; const float* bt1; const float* wt2; const float* bt2;
    const int* flag;
    const ushort_t* WTb;
    ushort_t* XqrB;
    ushort_t* rel_attn; ushort_t* rel_msg;
    ushort_t* dt_attn;  ushort_t* dt_msg;
    ushort_t* node_attn; ushort_t* node_msg;
    int* deg;
};

__global__ __launch_bounds__(256) void tabs_hist_kernel(TabArgs a)
{
    const int nb  = gridDim.x;
    const int bid = blockIdx.x;
    const int tid = threadIdx.x;

    __shared__ float hbuf[4][IN_DIM];                       // 2 KB
    __shared__ __align__(16) ushort_t stage[4][16 * STG];   // 25.6 KB

    {   // node MFMA projection; one 64-row unit per block (TAB_NB = #units)
        const int wid  = tid >> 6;
        const int lane = tid & 63;
        const int m16  = lane & 15;
        const int q    = lane >> 4;
        ushort_t* st = &stage[wid][0];
        for (int u = bid; u < (N_NODE + 63) / 64; u += nb) {
            const int nbase = u * 64;
            const int row   = nbase + wid * 16 + m16;
            const int rowc  = row < N_NODE ? row : N_NODE - 1;
            v8s afr[4];
            #pragma unroll
            for (int c = 0; c < 4; ++c) {
                const float4 f0 = *(const float4*)(a.hidden + (size_t)rowc * 128 + 32 * c + 8 * q);
                const float4 f1 = *(const float4*)(a.hidden + (size_t)rowc * 128 + 32 * c + 8 * q + 4);
                v8s v;
                v[0] = (short)f2bu(f0.x); v[1] = (short)f2bu(f0.y);
                v[2] = (short)f2bu(f0.z); v[3] = (short)f2bu(f0.w);
                v[4] = (short)f2bu(f1.x); v[5] = (short)f2bu(f1.y);
                v[6] = (short)f2bu(f1.z); v[7] = (short)f2bu(f1.w);
                afr[c] = v;
            }
            #pragma unroll
            for (int t = 0; t < 12; ++t) {
                v4f acc = {0.f, 0.f, 0.f, 0.f};
                #pragma unroll
                for (int c = 0; c < 4; ++c) {
                    const v8s bfr = *(const v8s*)(a.WTb + (size_t)(16 * t + m16) * 128 + 32 * c + 8 * q);
                    acc = __builtin_amdgcn_mfma_f32_16x16x32_bf16(afr[c], bfr, acc, 0, 0, 0);
                }
                #pragma unroll
                for (int r = 0; r < 4; ++r)          // stage (wave-local, no barrier)
                    st[(4 * q + r) * STG + 16 * t + m16] = f2bu(acc[r]);
            }
            // coalesced stores from LDS (same wave wrote it; hw waitcnt orders)
            #pragma unroll
            for (int k = 0; k < 2; ++k) {            // attn: 16 rows x 128 B
                const int i   = lane + 64 * k;       // 0..127
                const int rr  = i >> 3, seg = i & 7;
                const int nd  = nbase + wid * 16 + rr;
                if (nd < N_NODE) {
                    const uint4 vv = *(const uint4*)&st[rr * STG + seg * 8];
                    *(uint4*)&a.node_attn[(size_t)nd * 64 + seg * 8] = vv;
                }
            }
            #pragma unroll
            for (int k = 0; k < 4; ++k) {            // msg: 16 rows x 256 B
                const int i   = lane + 64 * k;       // 0..255
                const int rr  = i >> 4, seg = i & 15;
                const int nd  = nbase + wid * 16 + rr;
                if (nd < N_NODE) {
                    const uint4 vv = *(const uint4*)&st[rr * STG + 64 + seg * 8];
                    *(uint4*)&a.node_msg[(size_t)nd * 128 + seg * 8] = vv;
                }
            }
        }
    }
    {   // rel tabs, 2 per block
        const int half = tid >> 7, t = tid & 127;
        for (int u = bid; u < (N_RELV + 1) / 2; u += nb) {
            const int r = 2 * u + half;
            if (r < N_RELV) hbuf[half][t] = a.rela[(size_t)r * IN_DIM + t];
            __syncthreads();
            if (r < N_RELV) {
                if (t < ATTN_DIM) {
                    float x = 0.f;
                    #pragma unroll 8
                    for (int d = 0; d < IN_DIM; ++d) x += hbuf[half][d] * a.Wr[d * ATTN_DIM + t];
                    a.rel_attn[(size_t)r * ATTN_DIM + t] = f2bu(x);
                }
                float m = 0.f;
                #pragma unroll 8
                for (int d = 0; d < IN_DIM; ++d) m += hbuf[half][d] * a.Wh[d * OUT_DIM + t];
                a.rel_msg[(size_t)r * OUT_DIM + t] = f2bu(m);
            }
            __syncthreads();
        }
    }
    {   // dt tabs, 2 per block
        const int half = tid >> 7, t = tid & 127;
        for (int u = bid; u < (N_DT + 1) / 2; u += nb) {
            const int i = 2 * u + half;
            if (i < N_DT) {
                const float dt = (float)(i - 365);
                hbuf[half][t] = a.wt1[t] * dt + a.bt1[t] + sinf(a.wt2[t] * dt + a.bt2[t]);
            }
            __syncthreads();
            if (i < N_DT) {
                if (t < ATTN_DIM) {
                    float x = 0.f;
                    #pragma unroll 8
                    for (int d = 0; d < IN_DIM; ++d) x += hbuf[half][d] * a.Wtau[d * ATTN_DIM + t];
                    a.dt_attn[(size_t)i * ATTN_DIM + t] = f2bu(x);
                }
                float m = 0.f;
                #pragma unroll 8
                for (int d = 0; d < IN_DIM; ++d) m += hbuf[half][d] * a.Wh[d * OUT_DIM + t];
                a.dt_msg[(size_t)i * OUT_DIM + t] = f2bu(m);
            }
            __syncthreads();
        }
    }
    {   // qr tab, 4 per block (16 units)
        const int sq = tid >> 6, lane = tid & 63;
        const int i64 = a.flag[0];
        for (int u = bid; u < N_QUERY / 4; u += nb) {
            const int qq  = 4 * u + sq;
            const int rel = clampi(a.q_rel[i64 ? 2 * qq : qq], 0, N_RELV - 1);
            const float2 v = ((const float2*)(a.rela + (size_t)rel * IN_DIM))[lane];
            hbuf[sq][2 * lane] = v.x; hbuf[sq][2 * lane + 1] = v.y;
            __syncthreads();
            float acc = a.Wqrb[lane];
            #pragma unroll 8
            for (int d = 0; d < IN_DIM; ++d) acc += hbuf[sq][d] * a.WqrW[d * ATTN_DIM + lane];
            a.XqrB[(size_t)qq * ATTN_DIM + lane] = f2bu(acc);
            __syncthreads();
        }
    }
    {   // degree histogram
        const int i64 = a.flag[0];
        const int gsz = nb * 256;
        for (int e = bid * 256 + tid; e < N_EDGE; e += gsz) {
            int obj = i64 ? a.edges[(size_t)e * 14 + 12] : a.edges[(size_t)e * 7 + 6];
            obj = clampi(obj, 0, N_NODE - 1);
            atomicAdd(&a.deg[obj], 1);
        }
    }
}

// ---------------------------------------------------------------------------
// K2: one-dispatch scan, 196 blocks. Block b redundantly sums deg[0..256b)
// for its base (L2-resident), then block-scans its own 256-chunk.
// No grid sync, no serial single-block tail.
// ---------------------------------------------------------------------------
__global__ __launch_bounds__(256) void scan_fused_kernel(
    const int* __restrict__ deg, int* __restrict__ offs, int* __restrict__ cursor)
{
    const int b = blockIdx.x, tid = threadIdx.x;
    const int lane = tid & 63, wid = tid >> 6;

    // base = sum(deg[0 .. 256b))
    int priv = 0;
    for (int j = tid; j < b * 256; j += 256) priv += deg[j];
    #pragma unroll
    for (int o = 32; o > 0; o >>= 1) priv += __shfl_down(priv, o, 64);
    __shared__ int red[4];
    if (lane == 0) red[wid] = priv;
    __syncthreads();
    const int base = red[0] + red[1] + red[2] + red[3];
    __syncthreads();

    // block-scan own chunk
    const int i = b * 256 + tid;
    const int v = (i < N_NODE) ? deg[i] : 0;
    __shared__ int s[256];
    int acc = v;
    s[tid] = acc; __syncthreads();
    #pragma unroll
    for (int o = 1; o < 256; o <<= 1) {
        const int t = (tid >= o) ? s[tid - o] : 0;
        __syncthreads();
        acc += t; s[tid] = acc;
        __syncthreads();
    }
    if (i < N_NODE) {
        const int ex = base + acc - v;
        offs[i] = ex; cursor[i] = ex;
    }
    if (b == 0 && tid == 0) offs[N_NODE] = N_EDGE;
}

// ---------------------------------------------------------------------------
// K3: per-edge alpha. 16 lanes per edge (4 edges/wave).
// meta.x = sub | (di<<17), meta.y = rel, metaW = alpha.
// ---------------------------------------------------------------------------
__global__ __launch_bounds__(256) void alpha_kernel(
    const int* __restrict__ edges, const int* __restrict__ q_tau,
    const ushort_t* __restrict__ node_attn, const ushort_t* __restrict__ rel_attn,
    const ushort_t* __restrict__ dt_attn,  const ushort_t* __restrict__ Xqr,
    const float* __restrict__ w_alpha_W, const float* __restrict__ w_alpha_b,
    const int* __restrict__ flag, int* __restrict__ cursor,
    int2* __restrict__ metaA, float* __restrict__ metaW)
{
    const int g   = threadIdx.x & 15;
    const int e   = blockIdx.x * 16 + (threadIdx.x >> 4);
    const int i64 = flag[0];

    int r, rel, tau, sub, obj;
    parse_edge(edges, e, i64, r, rel, tau, sub, obj);
    const int tq = q_tau[i64 ? 2 * r : r];
    if (tau < 0) tau = tq;
    const int di = clampi(tau - tq + 365, 0, N_DT - 1);

    const uint2 xs = *(const uint2*)(node_attn + (size_t)sub * ATTN_DIM + 4 * g);
    const uint2 xr = *(const uint2*)(rel_attn + (size_t)rel * ATTN_DIM + 4 * g);
    const uint2 xt = *(const uint2*)(dt_attn  + (size_t)di  * ATTN_DIM + 4 * g);
    const uint2 xq = *(const uint2*)(Xqr      + (size_t)r   * ATTN_DIM + 4 * g);
    const float4 w = *(const float4*)(w_alpha_W + 4 * g);

    const float s0 = blo(xs.x) + blo(xr.x) + blo(xt.x) + blo(xq.x);
    const float s1 = bhi(xs.x) + bhi(xr.x) + bhi(xt.x) + bhi(xq.x);
    const float s2 = blo(xs.y) + blo(xr.y) + blo(xt.y) + blo(xq.y);
    const float s3 = bhi(xs.y) + bhi(xr.y) + bhi(xt.y) + bhi(xq.y);

    float v = fmaxf(s0, 0.f) * w.x + fmaxf(s1, 0.f) * w.y
            + fmaxf(s2, 0.f) * w.z + fmaxf(s3, 0.f) * w.w;
    v += __shfl_down(v, 8, 16);
    v += __shfl_down(v, 4, 16);
    v += __shfl_down(v, 2, 16);
    v += __shfl_down(v, 1, 16);

    if (g == 0) {
        const float alpha = 1.f / (1.f + __expf(-(v + w_alpha_b[0])));
        const int pos = atomicAdd(&cursor[obj], 1);
        metaA[pos] = make_int2(sub | (di << 17), rel);
        metaW[pos] = alpha;
    }
}

// ---------------------------------------------------------------------------
// K4: per-node aggregation, no atomics.
// ---------------------------------------------------------------------------
__device__ __forceinline__ void agg_step(
    int2 m, float al, int lane,
    const ushort_t* __restrict__ node_msg, const ushort_t* __restrict__ rel_msg,
    const ushort_t* __restrict__ dt_msg, float& a0, float& a1)
{
    const int sub = m.x & 0x1FFFF;
    const int di  = m.x >> 17;
    const int rel = m.y;
    const uint_t am = *(const uint_t*)(node_msg + (size_t)sub * 128 + 2 * lane);
    const uint_t bm = *(const uint_t*)(rel_msg  + (size_t)rel * 128 + 2 * lane);
    const uint_t tm = *(const uint_t*)(dt_msg   + (size_t)di  * 128 + 2 * lane);
    a0 += al * (blo(am) + blo(bm) + blo(tm));
    a1 += al * (bhi(am) + bhi(bm) + bhi(tm));
}

__global__ __launch_bounds__(256) void agg_kernel(
    const int* __restrict__ offs, const int2* __restrict__ metaA,
    const float* __restrict__ metaW,
    const ushort_t* __restrict__ node_msg, const ushort_t* __restrict__ rel_msg,
    const ushort_t* __restrict__ dt_msg, float* __restrict__ out)
{
    const int lane = threadIdx.x & 63;
    const int n    = blockIdx.x * 4 + (threadIdx.x >> 6);

    const int lo = offs[n], hi = offs[n + 1];
    float a0 = 0.f, a1 = 0.f;
    int j = lo;
    for (; j + 1 < hi; j += 2) {
        const int2 m0 = metaA[j];     const float w0 = metaW[j];
        const int2 m1 = metaA[j + 1]; const float w1 = metaW[j + 1];
        agg_step(m0, w0, lane, node_msg, rel_msg, dt_msg, a0, a1);
        agg_step(m1, w1, lane, node_msg, rel_msg, dt_msg, a0, a1);
    }
    if (j < hi)
        agg_step(metaA[j], metaW[j], lane, node_msg, rel_msg, dt_msg, a0, a1);

    ((float2*)(out + (size_t)n * OUT_DIM))[lane] = make_float2(a0, a1);
}

// ---------------------------------------------------------------------------
// Small-ws fallback: single-pass atomic edge kernel (uses tabs from K1).
// ---------------------------------------------------------------------------
__global__ __launch_bounds__(256) void edge_atomic_kernel(
    const int* __restrict__ edges, const int* __restrict__ q_tau,
    const ushort_t* __restrict__ node_attn, const ushort_t* __restrict__ node_msg,
    const ushort_t* __restrict__ rel_attn,  const ushort_t* __restrict__ rel_msg,
    const ushort_t* __restrict__ dt_attn,   const ushort_t* __restrict__ dt_msg,
    const ushort_t* __restrict__ Xqr,
    const float* __restrict__ w_alpha_W, const float* __restrict__ w_alpha_b,
    const int* __restrict__ flag, float* __restrict__ out)
{
    const int lane = threadIdx.x & 63;
    const int e    = blockIdx.x * 4 + (threadIdx.x >> 6);
    const int i64  = flag[0];

    int r, rel, tau, sub, obj;
    parse_edge(edges, e, i64, r, rel, tau, sub, obj);
    const int tq = q_tau[i64 ? 2 * r : r];
    if (tau < 0) tau = tq;
    const int di = clampi(tau - tq + 365, 0, N_DT - 1);

    const float xs = bu2f(node_attn[(size_t)sub * ATTN_DIM + lane]);
    const float xr = bu2f(rel_attn[(size_t)rel * ATTN_DIM + lane]);
    const float xt = bu2f(dt_attn[(size_t)di  * ATTN_DIM + lane]);
    const float xq = bu2f(Xqr[(size_t)r * ATTN_DIM + lane]);

    float v = fmaxf(xs + xr + xq + xt, 0.f) * w_alpha_W[lane];
    #pragma unroll
    for (int off = 32; off > 0; off >>= 1)
        v += __shfl_down(v, off, 64);
    v = __shfl(v, 0, 64);
    const float alpha = 1.f / (1.f + __expf(-(v + w_alpha_b[0])));

    const uint_t am = *(const uint_t*)(node_msg + (size_t)sub * 128 + 2 * lane);
    const uint_t bm = *(const uint_t*)(rel_msg  + (size_t)rel * 128 + 2 * lane);
    const uint_t tm = *(const uint_t*)(dt_msg   + (size_t)di  * 128 + 2 * lane);
    const float mx = blo(am) + blo(bm) + blo(tm);
    const float my = bhi(am) + bhi(bm) + bhi(tm);

    float* dst = out + (size_t)obj * OUT_DIM;
    atomicAdd(dst + 2 * lane,     alpha * mx);
    atomicAdd(dst + 2 * lane + 1, alpha * my);
}

// ===========================================================================
extern "C" void kernel_launch(void* const* d_in, const int* in_sizes, int n_in,
                              void* d_out, int out_size, void* d_ws, size_t ws_size,
                              hipStream_t stream)
{
    const int*   q_rel  = (const int*)d_in[1];
    const int*   q_tau  = (const int*)d_in[2];
    const float* hidden = (const float*)d_in[3];
    const int*   edges  = (const int*)d_in[4];
    const float* rela   = (const float*)d_in[7];
    const float* Ws     = (const float*)d_in[8];
    const float* Wr     = (const float*)d_in[9];
    const float* WqrW   = (const float*)d_in[10];
    const float* Wqrb   = (const float*)d_in[11];
    const float* Wtau   = (const float*)d_in[12];
    const float* waW    = (const float*)d_in[13];
    const float* wab    = (const float*)d_in[14];
    const float* Wh     = (const float*)d_in[15];
    const float* wt1    = (const float*)d_in[16];
    const float* bt1    = (const float*)d_in[17];
    const float* wt2    = (const float*)d_in[18];
    const float* bt2    = (const float*)d_in[19];
    float* out = (float*)d_out;

    // --- workspace carve (256-B aligned chunks) ---
    char* p = (char*)d_ws;
    size_t off = 0;
    auto carve = [&](size_t bytes) {
        char* q = p + off;
        off = (off + bytes + 255) & ~(size_t)255;
        return q;
    };
    int*      flag      = (int*)     carve(64);
    ushort_t* WTb       = (ushort_t*)carve((size_t)192 * 128 * 2);
    ushort_t* XqrB      = (ushort_t*)carve((size_t)N_QUERY * ATTN_DIM * 2);
    ushort_t* rel_attn  = (ushort_t*)carve((size_t)N_RELV * ATTN_DIM * 2);
    ushort_t* rel_msg   = (ushort_t*)carve((size_t)N_RELV * OUT_DIM * 2);
    ushort_t* dt_attn   = (ushort_t*)carve((size_t)N_DT * ATTN_DIM * 2);
    ushort_t* dt_msg    = (ushort_t*)carve((size_t)N_DT * OUT_DIM * 2);
    ushort_t* node_attn = (ushort_t*)carve((size_t)N_NODE * ATTN_DIM * 2);
    ushort_t* node_msg  = (ushort_t*)carve((size_t)N_NODE * OUT_DIM * 2);
    int*      deg       = (int*)     carve((size_t)N_NODE * 4);
    int*      offs      = (int*)     carve(((size_t)N_NODE + 1) * 4);
    int*      cursor    = (int*)     carve((size_t)N_NODE * 4);
    int2*     metaA     = (int2*)    carve((size_t)N_EDGE * 8);
    float*    metaW     = (float*)   carve((size_t)N_EDGE * 4);
    const size_t need_csr = off;

    init_kernel<<<1, 256, 0, stream>>>(edges, Ws, Wh, flag, WTb, deg);

    TabArgs ta;
    ta.edges = edges; ta.q_rel = q_rel;
    ta.hidden = hidden; ta.rela = rela;
    ta.Wr = Wr; ta.WqrW = WqrW; ta.Wqrb = Wqrb;
    ta.Wtau = Wtau; ta.Wh = Wh;
    ta.wt1 = wt1; ta.bt1 = bt1; ta.wt2 = wt2; ta.bt2 = bt2;
    ta.flag = flag; ta.WTb = WTb; ta.XqrB = XqrB;
    ta.rel_attn = rel_attn; ta.rel_msg = rel_msg;
    ta.dt_attn = dt_attn;   ta.dt_msg = dt_msg;
    ta.node_attn = node_attn; ta.node_msg = node_msg;
    ta.deg = deg;

    tabs_hist_kernel<<<TAB_NB, 256, 0, stream>>>(ta);

    if (ws_size >= need_csr) {
        scan_fused_kernel<<<NCH, 256, 0, stream>>>(deg, offs, cursor);
        alpha_kernel<<<N_EDGE / 16, 256, 0, stream>>>(edges, q_tau, node_attn,
                                                      rel_attn, dt_attn, XqrB,
                                                      waW, wab, flag, cursor,
                                                      metaA, metaW);
        agg_kernel  <<<N_NODE / 4,  256, 0, stream>>>(offs, metaA, metaW,
                                                      node_msg, rel_msg, dt_msg, out);
    } else {
        (void)hipMemsetAsync(out, 0, (size_t)out_size * sizeof(float), stream);
        edge_atomic_kernel<<<N_EDGE / 4, 256, 0, stream>>>(edges, q_tau,
                                                           node_attn, node_msg,
                                                           rel_attn, rel_msg,
                                                           dt_attn, dt_msg, XqrB,
                                                           waW, wab, flag, out);
    }
}